// Round 11
// baseline (349.843 us; speedup 1.0000x reference)
//
#include <hip/hip_runtime.h>
#include <cfloat>
#include <cstddef>

// VQEmbeddingEMA inference forward — R10 frame + stream-once epilogue (no xv[] array).
// x:   [B=32, N*D=512, L=1024] f32
// emb: [N=8, M=512, D=64] f32
// out: quantized_st [B,512,L] (16777216 f32) ++ loss (1) ++ perplexity (1)

#define N_G   8
#define M_CB  512
#define D_DIM 64
#define B_SZ  32
#define L_SEQ 1024
#define TOKENS (N_G * B_SZ * L_SEQ)                     // 262144
#define OUT_ELEMS ((size_t)B_SZ * N_G * D_DIM * L_SEQ)  // 16777216
#define MARGIN 2560
#define NLOSS 64

typedef _Float16 f16x8 __attribute__((ext_vector_type(8)));
typedef float    f32x4 __attribute__((ext_vector_type(4)));

// ---------------- workspace layout ----------------
//   [0,       524288)  e_f16  : codebook as f16, scaled by -2:  [n][m][d]
//   [524288,  540672)  e2p    : 1.0f + ||e||^2   (prescreen C-init table)
//   [540672,  557056)  e2raw  : ||e||^2          (exact fp32 rescore table)
//   [557056,  573440)  counts : int histogram [n][m]
//   [573440,  573696)  lossAcc: float[64]
#define EF_OFF   0
#define E2P_OFF  524288
#define E2R_OFF  540672
#define CNT_OFF  557056
#define LOSS_OFF 573440

__global__ void vq_ef16_kernel(const float* __restrict__ emb, unsigned int* __restrict__ ef) {
    int i = blockIdx.x * blockDim.x + threadIdx.x;    // handles 2 elements
    if (i < N_G * M_CB * D_DIM / 2) {
        float2 v = reinterpret_cast<const float2*>(emb)[i];
        _Float16 h0 = (_Float16)(-2.0f * v.x);
        _Float16 h1 = (_Float16)(-2.0f * v.y);
        unsigned int u0 = (unsigned int)__builtin_bit_cast(unsigned short, h0);
        unsigned int u1 = (unsigned int)__builtin_bit_cast(unsigned short, h1);
        ef[i] = u0 | (u1 << 16);
    }
}

__global__ void vq_e2_kernel(const float* __restrict__ emb,
                             float* __restrict__ e2raw,
                             float* __restrict__ e2p) {
    int i = blockIdx.x * blockDim.x + threadIdx.x;
    if (i < N_G * M_CB) {
        const float* e = emb + (size_t)i * D_DIM;
        float s0 = 0.f, s1 = 0.f, s2 = 0.f, s3 = 0.f;
        #pragma unroll
        for (int d = 0; d < D_DIM; d += 4) {
            s0 = fmaf(e[d+0], e[d+0], s0);
            s1 = fmaf(e[d+1], e[d+1], s1);
            s2 = fmaf(e[d+2], e[d+2], s2);
            s3 = fmaf(e[d+3], e[d+3], s3);
        }
        float s = (s0 + s1) + (s2 + s3);
        e2raw[i] = s;
        e2p[i] = 1.0f + s;
    }
}

// ---------------- MFMA main kernel (R10 frame, stream-once epilogue) ----------------
__global__ __launch_bounds__(256, 4)
void vq_mfma_kernel(const float* __restrict__ x,
                    const float* __restrict__ emb,
                    const unsigned short* __restrict__ ef16,
                    const float* __restrict__ e2raw,
                    const float* __restrict__ e2p,
                    float* __restrict__ out,
                    int* __restrict__ counts,
                    float* __restrict__ lossAcc) {
    __shared__ int hist[M_CB];
    __shared__ int cands[4][4][16][8];   // [wave][strip][col][4 lane-slots x top2]
    __shared__ __align__(16) short ebuf[4 * 16 * 72];   // 4 tiles x 16 rows x 72 shorts

    const int tid  = threadIdx.x;
    hist[tid] = 0;
    hist[tid + 256] = 0;

    const int lane = tid & 63;
    const int wv   = tid >> 6;
    const int cc   = lane & 15;          // token col within strip / A-row (m)
    const int kl   = lane >> 4;          // k-chunk id / D row-group
    const int kl4  = kl << 2;

    const int bb  = blockIdx.x;          // [0,1024)
    const int n   = bb >> 7;
    const int rem = bb & 127;
    const int b   = rem >> 2;
    const int l0  = ((rem & 3) << 8) + (wv << 6);   // wave's token base

    const float* __restrict__ xg = x + (size_t)(b * N_G + n) * D_DIM * L_SEQ;
    const unsigned short* __restrict__ eg16 = ef16 + (size_t)n * M_CB * D_DIM;
    const float* __restrict__ e2pg = e2p + n * M_CB;

    // staging coords (chunk ids tid, tid+256 of 512 per outer)
    const int st_t0 = tid >> 7;
    const int st_r0 = (tid >> 3) & 15;
    const int st_c0 = tid & 7;
    const int st_o0 = st_t0 * 1152 + st_r0 * 72 + st_c0 * 8;
    const int st_o1 = (st_t0 + 2) * 1152 + st_r0 * 72 + st_c0 * 8;

    // ---- load X fragments (global -> f16), accumulate Sum(x^2) on the fly ----
    f16x8 xf[4][2];
    float x2p = 0.f;
    #pragma unroll
    for (int s = 0; s < 4; ++s) {
        const int tok = l0 + s * 16 + cc;
        #pragma unroll
        for (int kc = 0; kc < 2; ++kc) {
            const int dbase = kc * 32 + kl * 8;
            f16x8 v;
            #pragma unroll
            for (int j = 0; j < 8; ++j) {
                const float xs = xg[(size_t)(dbase + j) * L_SEQ + tok];
                x2p = fmaf(xs, xs, x2p);
                v[j] = (_Float16)xs;
            }
            xf[s][kc] = v;
        }
    }

    int t1[4], t2[4];
    #pragma unroll
    for (int s = 0; s < 4; ++s) { t1[s] = 0x7FFFFFFF; t2[s] = 0x7FFFFFFF; }

    // ---- prescreen: 8 outer chunks x 4 m-tiles; codebook via LDS ----
    for (int outer = 0; outer < 8; ++outer) {
        {
            const unsigned short* gsrc = eg16 + outer * 4096;
            const uint4 g0 = *reinterpret_cast<const uint4*>(gsrc + tid * 8);
            const uint4 g1 = *reinterpret_cast<const uint4*>(gsrc + 2048 + tid * 8);
            *reinterpret_cast<uint4*>(&ebuf[st_o0]) = g0;
            *reinterpret_cast<uint4*>(&ebuf[st_o1]) = g1;
        }
        __syncthreads();

        #pragma unroll
        for (int ml = 0; ml < 4; ++ml) {
            const short* erow = &ebuf[ml * 1152 + cc * 72 + kl * 8];
            const f16x8 ea0 = *reinterpret_cast<const f16x8*>(erow);
            const f16x8 ea1 = *reinterpret_cast<const f16x8*>(erow + 32);
            const int mt = outer * 4 + ml;
            const f32x4 ce2 = *reinterpret_cast<const f32x4*>(e2pg + mt * 16 + kl4);
            const int mb = mt * 16 + kl4;

            #pragma unroll
            for (int s = 0; s < 4; ++s) {
                f32x4 dacc = __builtin_amdgcn_mfma_f32_16x16x32_f16(ea0, xf[s][0], ce2,  0, 0, 0);
                dacc       = __builtin_amdgcn_mfma_f32_16x16x32_f16(ea1, xf[s][1], dacc, 0, 0, 0);
                const int p0 = (__float_as_int(dacc[0]) & ~511) | (mb + 0);
                const int p1 = (__float_as_int(dacc[1]) & ~511) | (mb + 1);
                const int p2 = (__float_as_int(dacc[2]) & ~511) | (mb + 2);
                const int p3 = (__float_as_int(dacc[3]) & ~511) | (mb + 3);
                int mn = min(p0, p1), mx = max(p0, p1);
                t2[s] = min(t2[s], max(min(t1[s], mx), mn));   // med3(t1,p0,p1)
                t1[s] = min(t1[s], mn);
                mn = min(p2, p3); mx = max(p2, p3);
                t2[s] = min(t2[s], max(min(t1[s], mx), mn));
                t1[s] = min(t1[s], mn);
            }
        }
        __syncthreads();
    }

    // ---- hand candidates to owning lane via LDS ----
    #pragma unroll
    for (int s = 0; s < 4; ++s) {
        cands[wv][s][cc][kl * 2 + 0] = t1[s];
        cands[wv][s][cc][kl * 2 + 1] = t2[s];
    }
    __syncthreads();

    const int tok = l0 + lane;           // lane owns token: strip = kl, col = cc
    int cd[8];
    #pragma unroll
    for (int j = 0; j < 8; ++j) cd[j] = cands[wv][kl][cc][j];
    int pmin = cd[0];
    #pragma unroll
    for (int j = 1; j < 8; ++j) pmin = min(pmin, cd[j]);

    const float* __restrict__ eg  = emb + (size_t)n * M_CB * D_DIM;
    const float* __restrict__ e2g = e2raw + n * M_CB;

    // ---- rescore all 8 candidates, x streamed ONCE per batch of 4 ----
    // (identical fp32 summation order per candidate as validated kernels:
    //  4 partials a0..a3 over q; dist = fma(-2, (a0+a1)+(a2+a3), e2))
    float dist[8];
    #pragma unroll
    for (int batch = 0; batch < 2; ++batch) {
        float a0[4] = {0.f, 0.f, 0.f, 0.f};
        float a1[4] = {0.f, 0.f, 0.f, 0.f};
        float a2[4] = {0.f, 0.f, 0.f, 0.f};
        float a3[4] = {0.f, 0.f, 0.f, 0.f};
        const float4* em4_0 = reinterpret_cast<const float4*>(eg + (size_t)(cd[batch*4+0] & 511) * D_DIM);
        const float4* em4_1 = reinterpret_cast<const float4*>(eg + (size_t)(cd[batch*4+1] & 511) * D_DIM);
        const float4* em4_2 = reinterpret_cast<const float4*>(eg + (size_t)(cd[batch*4+2] & 511) * D_DIM);
        const float4* em4_3 = reinterpret_cast<const float4*>(eg + (size_t)(cd[batch*4+3] & 511) * D_DIM);
        #pragma unroll
        for (int q = 0; q < 16; ++q) {
            const float x0 = xg[(size_t)(q*4+0) * L_SEQ + tok];
            const float x1 = xg[(size_t)(q*4+1) * L_SEQ + tok];
            const float x2 = xg[(size_t)(q*4+2) * L_SEQ + tok];
            const float x3 = xg[(size_t)(q*4+3) * L_SEQ + tok];
            const float4 e0 = em4_0[q];
            const float4 e1 = em4_1[q];
            const float4 e2v = em4_2[q];
            const float4 e3 = em4_3[q];
            a0[0] = fmaf(x0, e0.x, a0[0]); a1[0] = fmaf(x1, e0.y, a1[0]);
            a2[0] = fmaf(x2, e0.z, a2[0]); a3[0] = fmaf(x3, e0.w, a3[0]);
            a0[1] = fmaf(x0, e1.x, a0[1]); a1[1] = fmaf(x1, e1.y, a1[1]);
            a2[1] = fmaf(x2, e1.z, a2[1]); a3[1] = fmaf(x3, e1.w, a3[1]);
            a0[2] = fmaf(x0, e2v.x, a0[2]); a1[2] = fmaf(x1, e2v.y, a1[2]);
            a2[2] = fmaf(x2, e2v.z, a2[2]); a3[2] = fmaf(x3, e2v.w, a3[2]);
            a0[3] = fmaf(x0, e3.x, a0[3]); a1[3] = fmaf(x1, e3.y, a1[3]);
            a2[3] = fmaf(x2, e3.z, a2[3]); a3[3] = fmaf(x3, e3.w, a3[3]);
        }
        #pragma unroll
        for (int k = 0; k < 4; ++k) {
            const int m = cd[batch*4+k] & 511;
            dist[batch*4+k] = fmaf(-2.f, (a0[k] + a1[k]) + (a2[k] + a3[k]), e2g[m]);
        }
    }

    // ---- selection: identical masked compare chain as validated kernels ----
    float best1 = FLT_MAX, best2 = FLT_MAX;
    int   idx1  = 0x7FFFFFFF, idx2 = 0x7FFFFFFF;
    #pragma unroll
    for (int j = 0; j < 8; ++j) {
        if (cd[j] - pmin <= MARGIN) {
            const int m = cd[j] & 511;
            const float dv = dist[j];
            if (dv < best1 || (dv == best1 && m < idx1)) {
                best2 = best1; idx2 = idx1; best1 = dv; idx1 = m;
            } else if (dv < best2 || (dv == best2 && m < idx2)) {
                best2 = dv; idx2 = m;
            }
        }
    }

    // ---- fp64 rescue for near-ties (streams x once; same d-order) ----
    if (best2 - best1 < 1e-4f) {
        const float* eA = eg + (size_t)idx1 * D_DIM;
        const float* eB = eg + (size_t)idx2 * D_DIM;
        double dA = 0.0, dB = 0.0;
        #pragma unroll
        for (int d = 0; d < D_DIM; ++d) {
            const double xd = (double)xg[(size_t)d * L_SEQ + tok];
            const double da = xd - (double)eA[d];
            const double db = xd - (double)eB[d];
            dA = fma(da, da, dA);
            dB = fma(db, db, dB);
        }
        if (dB < dA || (dB == dA && idx2 < idx1)) { idx1 = idx2; best1 = best2; }
    }

    // ---- epilogue: out = q; loss = Sum(x^2) + best dist; histogram ----
    const size_t obase = (size_t)(b * N_G + n) * D_DIM * L_SEQ + (size_t)tok;
    const float* __restrict__ ebest = eg + (size_t)idx1 * D_DIM;
    #pragma unroll
    for (int d = 0; d < D_DIM; d += 4) {
        const float4 qv = *reinterpret_cast<const float4*>(ebest + d);
        out[obase + (size_t)(d+0) * L_SEQ] = qv.x;
        out[obase + (size_t)(d+1) * L_SEQ] = qv.y;
        out[obase + (size_t)(d+2) * L_SEQ] = qv.z;
        out[obase + (size_t)(d+3) * L_SEQ] = qv.w;
    }

    float sq = x2p + best1;
    #pragma unroll
    for (int off = 32; off > 0; off >>= 1)
        sq += __shfl_down(sq, off, 64);
    if (lane == 0)
        atomicAdd(&lossAcc[bb & (NLOSS - 1)], sq);

    atomicAdd(&hist[idx1], 1);
    __syncthreads();
    {
        const int base = n * M_CB;
        int c0 = hist[tid];
        int c1 = hist[tid + 256];
        if (c0) atomicAdd(&counts[base + tid], c0);
        if (c1) atomicAdd(&counts[base + tid + 256], c1);
    }
}

__global__ void vq_finalize_kernel(const int* __restrict__ counts,
                                   const float* __restrict__ lossAcc,
                                   float* __restrict__ outTail) {
    __shared__ float red[256];
    const int tid = threadIdx.x;
    float perp = 0.f;
    for (int n = 0; n < N_G; ++n) {
        float h = 0.f;
        for (int m = tid; m < M_CB; m += 256) {
            const float p = (float)counts[n * M_CB + m] * (1.0f / (B_SZ * L_SEQ));
            h += p * logf(p + 1e-10f);
        }
        red[tid] = h;
        __syncthreads();
        #pragma unroll
        for (int s = 128; s > 0; s >>= 1) {
            if (tid < s) red[tid] += red[tid + s];
            __syncthreads();
        }
        if (tid == 0) perp += expf(-red[0]);
        __syncthreads();
    }
    if (tid == 0) {
        float ls = 0.f;
        for (int j = 0; j < NLOSS; ++j) ls += lossAcc[j];
        outTail[0] = 0.25f * (ls / (float)OUT_ELEMS);
        outTail[1] = perp;
    }
}

extern "C" void kernel_launch(void* const* d_in, const int* in_sizes, int n_in,
                              void* d_out, int out_size, void* d_ws, size_t ws_size,
                              hipStream_t stream) {
    const float* x   = (const float*)d_in[0];
    const float* emb = (const float*)d_in[1];
    float* out = (float*)d_out;
    char*  ws  = (char*)d_ws;

    unsigned int* ef16u  = (unsigned int*)(ws + EF_OFF);
    float* e2p    = (float*)(ws + E2P_OFF);
    float* e2r    = (float*)(ws + E2R_OFF);
    int*   counts = (int*)(ws + CNT_OFF);
    float* lossA  = (float*)(ws + LOSS_OFF);

    hipMemsetAsync(ws + CNT_OFF, 0, N_G * M_CB * 4 + NLOSS * 4, stream);
    vq_ef16_kernel<<<(N_G * M_CB * D_DIM / 2 + 255) / 256, 256, 0, stream>>>(emb, ef16u);
    vq_e2_kernel<<<(N_G * M_CB + 255) / 256, 256, 0, stream>>>(emb, e2r, e2p);
    vq_mfma_kernel<<<TOKENS / 256, 256, 0, stream>>>(
        x, emb, (const unsigned short*)ef16u, e2r, e2p, out, counts, lossA);
    vq_finalize_kernel<<<1, 256, 0, stream>>>(counts, lossA, out + OUT_ELEMS);
}

// Round 12
// 88.033 us; speedup vs baseline: 3.9740x; 3.9740x over previous
//
#include <hip/hip_runtime.h>
#include <cfloat>
#include <cstddef>

// VQEmbeddingEMA inference forward — R10 frame + register-prefetched staging,
// merged prep, barrier-free finalize.
// x:   [B=32, N*D=512, L=1024] f32
// emb: [N=8, M=512, D=64] f32
// out: quantized_st [B,512,L] (16777216 f32) ++ loss (1) ++ perplexity (1)

#define N_G   8
#define M_CB  512
#define D_DIM 64
#define B_SZ  32
#define L_SEQ 1024
#define TOKENS (N_G * B_SZ * L_SEQ)                     // 262144
#define OUT_ELEMS ((size_t)B_SZ * N_G * D_DIM * L_SEQ)  // 16777216
#define MARGIN 2560
#define NLOSS 64

typedef _Float16 f16x8 __attribute__((ext_vector_type(8)));
typedef float    f32x4 __attribute__((ext_vector_type(4)));

// ---------------- workspace layout ----------------
//   [0,       524288)  e_f16  : codebook as f16, scaled by -2:  [n][m][d]
//   [524288,  540672)  e2p    : 1.0f + ||e||^2   (prescreen C-init table)
//   [540672,  557056)  e2raw  : ||e||^2          (exact fp32 rescore table)
//   [557056,  573440)  counts : int histogram [n][m]
//   [573440,  573696)  lossAcc: float[64]
#define EF_OFF   0
#define E2P_OFF  524288
#define E2R_OFF  540672
#define CNT_OFF  557056
#define LOSS_OFF 573440

// ---- merged prep: ef16 conversion (all blocks) + e2 tables (first blocks) ----
__global__ void vq_prep_kernel(const float* __restrict__ emb,
                               unsigned int* __restrict__ ef,
                               float* __restrict__ e2raw,
                               float* __restrict__ e2p) {
    const int i = blockIdx.x * blockDim.x + threadIdx.x;
    if (i < N_G * M_CB * D_DIM / 2) {
        float2 v = reinterpret_cast<const float2*>(emb)[i];
        _Float16 h0 = (_Float16)(-2.0f * v.x);
        _Float16 h1 = (_Float16)(-2.0f * v.y);
        unsigned int u0 = (unsigned int)__builtin_bit_cast(unsigned short, h0);
        unsigned int u1 = (unsigned int)__builtin_bit_cast(unsigned short, h1);
        ef[i] = u0 | (u1 << 16);
    }
    if (i < N_G * M_CB) {
        const float* e = emb + (size_t)i * D_DIM;
        float s0 = 0.f, s1 = 0.f, s2 = 0.f, s3 = 0.f;
        #pragma unroll
        for (int d = 0; d < D_DIM; d += 4) {
            s0 = fmaf(e[d+0], e[d+0], s0);
            s1 = fmaf(e[d+1], e[d+1], s1);
            s2 = fmaf(e[d+2], e[d+2], s2);
            s3 = fmaf(e[d+3], e[d+3], s3);
        }
        float s = (s0 + s1) + (s2 + s3);
        e2raw[i] = s;
        e2p[i] = 1.0f + s;
    }
}

// ---------------- MFMA main kernel (R10 + staged-chunk register prefetch) ----------------
__global__ __launch_bounds__(256, 4)
void vq_mfma_kernel(const float* __restrict__ x,
                    const float* __restrict__ emb,
                    const unsigned short* __restrict__ ef16,
                    const float* __restrict__ e2raw,
                    const float* __restrict__ e2p,
                    float* __restrict__ out,
                    int* __restrict__ counts,
                    float* __restrict__ lossAcc) {
    __shared__ int hist[M_CB];
    __shared__ int cands[4][4][16][8];   // [wave][strip][col][4 lane-slots x top2]
    __shared__ __align__(16) short ebuf[4 * 16 * 72];   // 4 tiles x 16 rows x 72 shorts

    const int tid  = threadIdx.x;
    hist[tid] = 0;
    hist[tid + 256] = 0;

    const int lane = tid & 63;
    const int wv   = tid >> 6;
    const int cc   = lane & 15;          // token col within strip / A-row (m)
    const int kl   = lane >> 4;          // k-chunk id / D row-group
    const int kl4  = kl << 2;

    const int bb  = blockIdx.x;          // [0,1024)
    const int n   = bb >> 7;
    const int rem = bb & 127;
    const int b   = rem >> 2;
    const int l0  = ((rem & 3) << 8) + (wv << 6);   // wave's token base

    const float* __restrict__ xg = x + (size_t)(b * N_G + n) * D_DIM * L_SEQ;
    const unsigned short* __restrict__ eg16 = ef16 + (size_t)n * M_CB * D_DIM;
    const float* __restrict__ e2pg = e2p + n * M_CB;

    // staging coords (chunk ids tid, tid+256 of 512 per outer)
    const int st_t0 = tid >> 7;
    const int st_r0 = (tid >> 3) & 15;
    const int st_c0 = tid & 7;
    const int st_o0 = st_t0 * 1152 + st_r0 * 72 + st_c0 * 8;
    const int st_o1 = (st_t0 + 2) * 1152 + st_r0 * 72 + st_c0 * 8;

    // ---- load X fragments (global -> f16), accumulate Sum(x^2) on the fly ----
    f16x8 xf[4][2];
    float x2p = 0.f;
    #pragma unroll
    for (int s = 0; s < 4; ++s) {
        const int tok = l0 + s * 16 + cc;
        #pragma unroll
        for (int kc = 0; kc < 2; ++kc) {
            const int dbase = kc * 32 + kl * 8;
            f16x8 v;
            #pragma unroll
            for (int j = 0; j < 8; ++j) {
                const float xs = xg[(size_t)(dbase + j) * L_SEQ + tok];
                x2p = fmaf(xs, xs, x2p);
                v[j] = (_Float16)xs;
            }
            xf[s][kc] = v;
        }
    }

    int t1[4], t2[4];
    #pragma unroll
    for (int s = 0; s < 4; ++s) { t1[s] = 0x7FFFFFFF; t2[s] = 0x7FFFFFFF; }

    // ---- prescreen: 8 outer chunks x 4 m-tiles; staged via LDS with
    //      UNCONDITIONAL register prefetch of the next chunk (issue-early) ----
    uint4 g0 = *reinterpret_cast<const uint4*>(eg16 + tid * 8);
    uint4 g1 = *reinterpret_cast<const uint4*>(eg16 + 2048 + tid * 8);

    for (int outer = 0; outer < 8; ++outer) {
        // write staged chunk to LDS (prev-iter reads completed by loop-end barrier)
        *reinterpret_cast<uint4*>(&ebuf[st_o0]) = g0;
        *reinterpret_cast<uint4*>(&ebuf[st_o1]) = g1;
        __syncthreads();                 // ebuf ready

        // prefetch next chunk into registers (clamped index, always executed)
        {
            const int nxt = (outer < 7) ? outer + 1 : 7;
            const unsigned short* gsrc = eg16 + nxt * 4096 + tid * 8;
            g0 = *reinterpret_cast<const uint4*>(gsrc);
            g1 = *reinterpret_cast<const uint4*>(gsrc + 2048);
        }

        #pragma unroll
        for (int ml = 0; ml < 4; ++ml) {
            const short* erow = &ebuf[ml * 1152 + cc * 72 + kl * 8];
            const f16x8 ea0 = *reinterpret_cast<const f16x8*>(erow);
            const f16x8 ea1 = *reinterpret_cast<const f16x8*>(erow + 32);
            const int mt = outer * 4 + ml;
            const f32x4 ce2 = *reinterpret_cast<const f32x4*>(e2pg + mt * 16 + kl4);
            const int mb = mt * 16 + kl4;

            #pragma unroll
            for (int s = 0; s < 4; ++s) {
                f32x4 dacc = __builtin_amdgcn_mfma_f32_16x16x32_f16(ea0, xf[s][0], ce2,  0, 0, 0);
                dacc       = __builtin_amdgcn_mfma_f32_16x16x32_f16(ea1, xf[s][1], dacc, 0, 0, 0);
                // dacc[r] = 1 + e2 - 2*dot > 0: int-monotone after mask|idx pack
                const int p0 = (__float_as_int(dacc[0]) & ~511) | (mb + 0);
                const int p1 = (__float_as_int(dacc[1]) & ~511) | (mb + 1);
                const int p2 = (__float_as_int(dacc[2]) & ~511) | (mb + 2);
                const int p3 = (__float_as_int(dacc[3]) & ~511) | (mb + 3);
                int mn = min(p0, p1), mx = max(p0, p1);
                t2[s] = min(t2[s], max(min(t1[s], mx), mn));   // med3(t1,p0,p1)
                t1[s] = min(t1[s], mn);
                mn = min(p2, p3); mx = max(p2, p3);
                t2[s] = min(t2[s], max(min(t1[s], mx), mn));
                t1[s] = min(t1[s], mn);
            }
        }
        __syncthreads();                 // all reads done before next write
    }

    // ---- hand candidates to owning lane via LDS ----
    #pragma unroll
    for (int s = 0; s < 4; ++s) {
        cands[wv][s][cc][kl * 2 + 0] = t1[s];
        cands[wv][s][cc][kl * 2 + 1] = t2[s];
    }
    __syncthreads();

    const int tok = l0 + lane;           // lane owns token: strip = kl, col = cc
    int cd[8];
    #pragma unroll
    for (int j = 0; j < 8; ++j) cd[j] = cands[wv][kl][cc][j];
    int pmin = cd[0];
    #pragma unroll
    for (int j = 1; j < 8; ++j) pmin = min(pmin, cd[j]);

    // ---- reload this token's x column (fp32, coalesced, L2-hot) ----
    float xv[D_DIM];
    #pragma unroll
    for (int d = 0; d < D_DIM; ++d)
        xv[d] = xg[(size_t)d * L_SEQ + tok];

    // ---- exact fp32 rescore of near-minimal candidates (R6/R10 validated path) ----
    const float* __restrict__ eg  = emb + (size_t)n * M_CB * D_DIM;
    const float* __restrict__ e2g = e2raw + n * M_CB;
    float best1 = FLT_MAX, best2 = FLT_MAX;
    int   idx1  = 0x7FFFFFFF, idx2 = 0x7FFFFFFF;
    for (int j = 0; j < 8; ++j) {
        if (cd[j] - pmin <= MARGIN) {
            const int m = cd[j] & 511;
            const float4* em4 = reinterpret_cast<const float4*>(eg + (size_t)m * D_DIM);
            float a0 = 0.f, a1 = 0.f, a2 = 0.f, a3 = 0.f;
            #pragma unroll
            for (int q = 0; q < 16; ++q) {
                const float4 e4 = em4[q];
                a0 = fmaf(xv[q*4+0], e4.x, a0);
                a1 = fmaf(xv[q*4+1], e4.y, a1);
                a2 = fmaf(xv[q*4+2], e4.z, a2);
                a3 = fmaf(xv[q*4+3], e4.w, a3);
            }
            const float dist = fmaf(-2.f, (a0 + a1) + (a2 + a3), e2g[m]);
            if (dist < best1 || (dist == best1 && m < idx1)) {
                best2 = best1; idx2 = idx1; best1 = dist; idx1 = m;
            } else if (dist < best2 || (dist == best2 && m < idx2)) {
                best2 = dist; idx2 = m;
            }
        }
    }

    // ---- fp64 rescue for near-ties (validated semantics) ----
    if (best2 - best1 < 1e-4f) {
        const float* eA = eg + (size_t)idx1 * D_DIM;
        const float* eB = eg + (size_t)idx2 * D_DIM;
        double dA = 0.0, dB = 0.0;
        #pragma unroll
        for (int d = 0; d < D_DIM; ++d) {
            const double da = (double)xv[d] - (double)eA[d];
            const double db = (double)xv[d] - (double)eB[d];
            dA = fma(da, da, dA);
            dB = fma(db, db, dB);
        }
        if (dB < dA || (dB == dA && idx2 < idx1)) { idx1 = idx2; best1 = best2; }
    }

    // ---- epilogue: out = q; loss = Sum(x^2) + best dist; histogram ----
    const size_t obase = (size_t)(b * N_G + n) * D_DIM * L_SEQ + (size_t)tok;
    const float* __restrict__ ebest = eg + (size_t)idx1 * D_DIM;
    #pragma unroll
    for (int d = 0; d < D_DIM; d += 4) {
        const float4 qv = *reinterpret_cast<const float4*>(ebest + d);
        out[obase + (size_t)(d+0) * L_SEQ] = qv.x;
        out[obase + (size_t)(d+1) * L_SEQ] = qv.y;
        out[obase + (size_t)(d+2) * L_SEQ] = qv.z;
        out[obase + (size_t)(d+3) * L_SEQ] = qv.w;
    }

    float sq = x2p + best1;
    #pragma unroll
    for (int off = 32; off > 0; off >>= 1)
        sq += __shfl_down(sq, off, 64);
    if (lane == 0)
        atomicAdd(&lossAcc[bb & (NLOSS - 1)], sq);

    atomicAdd(&hist[idx1], 1);
    __syncthreads();
    {
        const int base = n * M_CB;
        int c0 = hist[tid];
        int c1 = hist[tid + 256];
        if (c0) atomicAdd(&counts[base + tid], c0);
        if (c1) atomicAdd(&counts[base + tid + 256], c1);
    }
}

// ---- barrier-free finalize: wave w reduces n=2w,2w+1; one barrier total ----
__global__ void vq_finalize_kernel(const int* __restrict__ counts,
                                   const float* __restrict__ lossAcc,
                                   float* __restrict__ outTail) {
    __shared__ float ent[8];
    const int tid  = threadIdx.x;
    const int lane = tid & 63;
    const int wvid = tid >> 6;           // 4 waves

    #pragma unroll
    for (int h = 0; h < 2; ++h) {
        const int n = wvid * 2 + h;
        float s = 0.f;
        #pragma unroll
        for (int r = 0; r < 8; ++r) {
            const float p = (float)counts[n * M_CB + r * 64 + lane] * (1.0f / (B_SZ * L_SEQ));
            s += p * logf(p + 1e-10f);
        }
        #pragma unroll
        for (int off = 32; off > 0; off >>= 1)
            s += __shfl_down(s, off, 64);
        if (lane == 0) ent[n] = s;
    }
    __syncthreads();
    if (tid == 0) {
        float perp = 0.f;
        #pragma unroll
        for (int n = 0; n < 8; ++n) perp += expf(-ent[n]);
        float ls = 0.f;
        for (int j = 0; j < NLOSS; ++j) ls += lossAcc[j];
        outTail[0] = 0.25f * (ls / (float)OUT_ELEMS);
        outTail[1] = perp;
    }
}

extern "C" void kernel_launch(void* const* d_in, const int* in_sizes, int n_in,
                              void* d_out, int out_size, void* d_ws, size_t ws_size,
                              hipStream_t stream) {
    const float* x   = (const float*)d_in[0];
    const float* emb = (const float*)d_in[1];
    float* out = (float*)d_out;
    char*  ws  = (char*)d_ws;

    unsigned int* ef16u  = (unsigned int*)(ws + EF_OFF);
    float* e2p    = (float*)(ws + E2P_OFF);
    float* e2r    = (float*)(ws + E2R_OFF);
    int*   counts = (int*)(ws + CNT_OFF);
    float* lossA  = (float*)(ws + LOSS_OFF);

    hipMemsetAsync(ws + CNT_OFF, 0, N_G * M_CB * 4 + NLOSS * 4, stream);
    vq_prep_kernel<<<(N_G * M_CB * D_DIM / 2 + 255) / 256, 256, 0, stream>>>(emb, ef16u, e2r, e2p);
    vq_mfma_kernel<<<TOKENS / 256, 256, 0, stream>>>(
        x, emb, (const unsigned short*)ef16u, e2r, e2p, out, counts, lossA);
    vq_finalize_kernel<<<1, 256, 0, stream>>>(counts, lossA, out + OUT_ELEMS);
}

// Round 13
// 87.596 us; speedup vs baseline: 3.9938x; 1.0050x over previous
//
#include <hip/hip_runtime.h>
#include <cfloat>
#include <cstddef>

// VQEmbeddingEMA inference forward — R12 + double-buffered staging (1 barrier/chunk)
// + memset folded into prep.
// x:   [B=32, N*D=512, L=1024] f32
// emb: [N=8, M=512, D=64] f32
// out: quantized_st [B,512,L] (16777216 f32) ++ loss (1) ++ perplexity (1)

#define N_G   8
#define M_CB  512
#define D_DIM 64
#define B_SZ  32
#define L_SEQ 1024
#define TOKENS (N_G * B_SZ * L_SEQ)                     // 262144
#define OUT_ELEMS ((size_t)B_SZ * N_G * D_DIM * L_SEQ)  // 16777216
#define MARGIN 2560
#define NLOSS 64

typedef _Float16 f16x8 __attribute__((ext_vector_type(8)));
typedef float    f32x4 __attribute__((ext_vector_type(4)));

// ---------------- workspace layout ----------------
//   [0,       524288)  e_f16  : codebook as f16, scaled by -2:  [n][m][d]
//   [524288,  540672)  e2p    : 1.0f + ||e||^2   (prescreen C-init table)
//   [540672,  557056)  e2raw  : ||e||^2          (exact fp32 rescore table)
//   [557056,  573440)  counts : int histogram [n][m]
//   [573440,  573696)  lossAcc: float[64]
#define EF_OFF   0
#define E2P_OFF  524288
#define E2R_OFF  540672
#define CNT_OFF  557056
#define LOSS_OFF 573440

// ---- merged prep: ef16 conversion + e2 tables + counts/loss zeroing ----
__global__ void vq_prep_kernel(const float* __restrict__ emb,
                               unsigned int* __restrict__ ef,
                               float* __restrict__ e2raw,
                               float* __restrict__ e2p,
                               int* __restrict__ counts,
                               float* __restrict__ lossAcc) {
    const int i = blockIdx.x * blockDim.x + threadIdx.x;
    if (i < N_G * M_CB * D_DIM / 2) {
        float2 v = reinterpret_cast<const float2*>(emb)[i];
        _Float16 h0 = (_Float16)(-2.0f * v.x);
        _Float16 h1 = (_Float16)(-2.0f * v.y);
        unsigned int u0 = (unsigned int)__builtin_bit_cast(unsigned short, h0);
        unsigned int u1 = (unsigned int)__builtin_bit_cast(unsigned short, h1);
        ef[i] = u0 | (u1 << 16);
    }
    if (i < N_G * M_CB) {
        const float* e = emb + (size_t)i * D_DIM;
        float s0 = 0.f, s1 = 0.f, s2 = 0.f, s3 = 0.f;
        #pragma unroll
        for (int d = 0; d < D_DIM; d += 4) {
            s0 = fmaf(e[d+0], e[d+0], s0);
            s1 = fmaf(e[d+1], e[d+1], s1);
            s2 = fmaf(e[d+2], e[d+2], s2);
            s3 = fmaf(e[d+3], e[d+3], s3);
        }
        float s = (s0 + s1) + (s2 + s3);
        e2raw[i] = s;
        e2p[i] = 1.0f + s;
        counts[i] = 0;
    }
    if (i < NLOSS) lossAcc[i] = 0.f;
}

// ---------------- MFMA main kernel (dbuf staging, register prefetch) ----------------
__global__ __launch_bounds__(256, 4)
void vq_mfma_kernel(const float* __restrict__ x,
                    const float* __restrict__ emb,
                    const unsigned short* __restrict__ ef16,
                    const float* __restrict__ e2raw,
                    const float* __restrict__ e2p,
                    float* __restrict__ out,
                    int* __restrict__ counts,
                    float* __restrict__ lossAcc) {
    __shared__ int hist[M_CB];
    __shared__ int cands[4][4][16][8];   // [wave][strip][col][4 lane-slots x top2]
    __shared__ __align__(16) short ebuf[2][4 * 16 * 72];   // ping-pong staging

    const int tid  = threadIdx.x;
    hist[tid] = 0;
    hist[tid + 256] = 0;

    const int lane = tid & 63;
    const int wv   = tid >> 6;
    const int cc   = lane & 15;          // token col within strip / A-row (m)
    const int kl   = lane >> 4;          // k-chunk id / D row-group
    const int kl4  = kl << 2;

    const int bb  = blockIdx.x;          // [0,1024)
    const int n   = bb >> 7;
    const int rem = bb & 127;
    const int b   = rem >> 2;
    const int l0  = ((rem & 3) << 8) + (wv << 6);   // wave's token base

    const float* __restrict__ xg = x + (size_t)(b * N_G + n) * D_DIM * L_SEQ;
    const unsigned short* __restrict__ eg16 = ef16 + (size_t)n * M_CB * D_DIM;
    const float* __restrict__ e2pg = e2p + n * M_CB;

    // staging coords (chunk ids tid, tid+256 of 512 per outer)
    const int st_t0 = tid >> 7;
    const int st_r0 = (tid >> 3) & 15;
    const int st_c0 = tid & 7;
    const int st_o0 = st_t0 * 1152 + st_r0 * 72 + st_c0 * 8;
    const int st_o1 = (st_t0 + 2) * 1152 + st_r0 * 72 + st_c0 * 8;

    // ---- load X fragments (global -> f16), accumulate Sum(x^2) on the fly ----
    f16x8 xf[4][2];
    float x2p = 0.f;
    #pragma unroll
    for (int s = 0; s < 4; ++s) {
        const int tok = l0 + s * 16 + cc;
        #pragma unroll
        for (int kc = 0; kc < 2; ++kc) {
            const int dbase = kc * 32 + kl * 8;
            f16x8 v;
            #pragma unroll
            for (int j = 0; j < 8; ++j) {
                const float xs = xg[(size_t)(dbase + j) * L_SEQ + tok];
                x2p = fmaf(xs, xs, x2p);
                v[j] = (_Float16)xs;
            }
            xf[s][kc] = v;
        }
    }

    int t1[4], t2[4];
    #pragma unroll
    for (int s = 0; s < 4; ++s) { t1[s] = 0x7FFFFFFF; t2[s] = 0x7FFFFFFF; }

    // ---- prescreen: 8 outer chunks x 4 m-tiles; ping-pong LDS staging,
    //      ONE barrier per chunk, unconditional register prefetch ----
    uint4 g0 = *reinterpret_cast<const uint4*>(eg16 + tid * 8);
    uint4 g1 = *reinterpret_cast<const uint4*>(eg16 + 2048 + tid * 8);

    for (int outer = 0; outer < 8; ++outer) {
        short* const eb = ebuf[outer & 1];
        *reinterpret_cast<uint4*>(&eb[st_o0]) = g0;
        *reinterpret_cast<uint4*>(&eb[st_o1]) = g1;
        __syncthreads();                 // eb ready; prev buffer's reads all done

        // prefetch next chunk into registers (clamped index, always executed)
        {
            const int nxt = (outer < 7) ? outer + 1 : 7;
            const unsigned short* gsrc = eg16 + nxt * 4096 + tid * 8;
            g0 = *reinterpret_cast<const uint4*>(gsrc);
            g1 = *reinterpret_cast<const uint4*>(gsrc + 2048);
        }

        #pragma unroll
        for (int ml = 0; ml < 4; ++ml) {
            const short* erow = &eb[ml * 1152 + cc * 72 + kl * 8];
            const f16x8 ea0 = *reinterpret_cast<const f16x8*>(erow);
            const f16x8 ea1 = *reinterpret_cast<const f16x8*>(erow + 32);
            const int mt = outer * 4 + ml;
            const f32x4 ce2 = *reinterpret_cast<const f32x4*>(e2pg + mt * 16 + kl4);
            const int mb = mt * 16 + kl4;

            #pragma unroll
            for (int s = 0; s < 4; ++s) {
                f32x4 dacc = __builtin_amdgcn_mfma_f32_16x16x32_f16(ea0, xf[s][0], ce2,  0, 0, 0);
                dacc       = __builtin_amdgcn_mfma_f32_16x16x32_f16(ea1, xf[s][1], dacc, 0, 0, 0);
                // dacc[r] = 1 + e2 - 2*dot > 0: int-monotone after mask|idx pack
                const int p0 = (__float_as_int(dacc[0]) & ~511) | (mb + 0);
                const int p1 = (__float_as_int(dacc[1]) & ~511) | (mb + 1);
                const int p2 = (__float_as_int(dacc[2]) & ~511) | (mb + 2);
                const int p3 = (__float_as_int(dacc[3]) & ~511) | (mb + 3);
                int mn = min(p0, p1), mx = max(p0, p1);
                t2[s] = min(t2[s], max(min(t1[s], mx), mn));   // med3(t1,p0,p1)
                t1[s] = min(t1[s], mn);
                mn = min(p2, p3); mx = max(p2, p3);
                t2[s] = min(t2[s], max(min(t1[s], mx), mn));
                t1[s] = min(t1[s], mn);
            }
        }
        // no second barrier: next iter writes the other buffer; the single
        // barrier per iter separates all reads of buf b from its next write
    }

    // ---- hand candidates to owning lane via LDS ----
    #pragma unroll
    for (int s = 0; s < 4; ++s) {
        cands[wv][s][cc][kl * 2 + 0] = t1[s];
        cands[wv][s][cc][kl * 2 + 1] = t2[s];
    }
    __syncthreads();

    const int tok = l0 + lane;           // lane owns token: strip = kl, col = cc
    int cd[8];
    #pragma unroll
    for (int j = 0; j < 8; ++j) cd[j] = cands[wv][kl][cc][j];
    int pmin = cd[0];
    #pragma unroll
    for (int j = 1; j < 8; ++j) pmin = min(pmin, cd[j]);

    // ---- reload this token's x column (fp32, coalesced, L2-hot) ----
    float xv[D_DIM];
    #pragma unroll
    for (int d = 0; d < D_DIM; ++d)
        xv[d] = xg[(size_t)d * L_SEQ + tok];

    // ---- exact fp32 rescore of near-minimal candidates (validated path) ----
    const float* __restrict__ eg  = emb + (size_t)n * M_CB * D_DIM;
    const float* __restrict__ e2g = e2raw + n * M_CB;
    float best1 = FLT_MAX, best2 = FLT_MAX;
    int   idx1  = 0x7FFFFFFF, idx2 = 0x7FFFFFFF;
    for (int j = 0; j < 8; ++j) {
        if (cd[j] - pmin <= MARGIN) {
            const int m = cd[j] & 511;
            const float4* em4 = reinterpret_cast<const float4*>(eg + (size_t)m * D_DIM);
            float a0 = 0.f, a1 = 0.f, a2 = 0.f, a3 = 0.f;
            #pragma unroll
            for (int q = 0; q < 16; ++q) {
                const float4 e4 = em4[q];
                a0 = fmaf(xv[q*4+0], e4.x, a0);
                a1 = fmaf(xv[q*4+1], e4.y, a1);
                a2 = fmaf(xv[q*4+2], e4.z, a2);
                a3 = fmaf(xv[q*4+3], e4.w, a3);
            }
            const float dist = fmaf(-2.f, (a0 + a1) + (a2 + a3), e2g[m]);
            if (dist < best1 || (dist == best1 && m < idx1)) {
                best2 = best1; idx2 = idx1; best1 = dist; idx1 = m;
            } else if (dist < best2 || (dist == best2 && m < idx2)) {
                best2 = dist; idx2 = m;
            }
        }
    }

    // ---- fp64 rescue for near-ties (validated semantics) ----
    if (best2 - best1 < 1e-4f) {
        const float* eA = eg + (size_t)idx1 * D_DIM;
        const float* eB = eg + (size_t)idx2 * D_DIM;
        double dA = 0.0, dB = 0.0;
        #pragma unroll
        for (int d = 0; d < D_DIM; ++d) {
            const double da = (double)xv[d] - (double)eA[d];
            const double db = (double)xv[d] - (double)eB[d];
            dA = fma(da, da, dA);
            dB = fma(db, db, dB);
        }
        if (dB < dA || (dB == dA && idx2 < idx1)) { idx1 = idx2; best1 = best2; }
    }

    // ---- epilogue: out = q; loss = Sum(x^2) + best dist; histogram ----
    const size_t obase = (size_t)(b * N_G + n) * D_DIM * L_SEQ + (size_t)tok;
    const float* __restrict__ ebest = eg + (size_t)idx1 * D_DIM;
    #pragma unroll
    for (int d = 0; d < D_DIM; d += 4) {
        const float4 qv = *reinterpret_cast<const float4*>(ebest + d);
        out[obase + (size_t)(d+0) * L_SEQ] = qv.x;
        out[obase + (size_t)(d+1) * L_SEQ] = qv.y;
        out[obase + (size_t)(d+2) * L_SEQ] = qv.z;
        out[obase + (size_t)(d+3) * L_SEQ] = qv.w;
    }

    float sq = x2p + best1;
    #pragma unroll
    for (int off = 32; off > 0; off >>= 1)
        sq += __shfl_down(sq, off, 64);
    if (lane == 0)
        atomicAdd(&lossAcc[bb & (NLOSS - 1)], sq);

    atomicAdd(&hist[idx1], 1);
    __syncthreads();
    {
        const int base = n * M_CB;
        int c0 = hist[tid];
        int c1 = hist[tid + 256];
        if (c0) atomicAdd(&counts[base + tid], c0);
        if (c1) atomicAdd(&counts[base + tid + 256], c1);
    }
}

// ---- barrier-free finalize: wave w reduces n=2w,2w+1; one barrier total ----
__global__ void vq_finalize_kernel(const int* __restrict__ counts,
                                   const float* __restrict__ lossAcc,
                                   float* __restrict__ outTail) {
    __shared__ float ent[8];
    const int tid  = threadIdx.x;
    const int lane = tid & 63;
    const int wvid = tid >> 6;           // 4 waves

    #pragma unroll
    for (int h = 0; h < 2; ++h) {
        const int n = wvid * 2 + h;
        float s = 0.f;
        #pragma unroll
        for (int r = 0; r < 8; ++r) {
            const float p = (float)counts[n * M_CB + r * 64 + lane] * (1.0f / (B_SZ * L_SEQ));
            s += p * logf(p + 1e-10f);
        }
        #pragma unroll
        for (int off = 32; off > 0; off >>= 1)
            s += __shfl_down(s, off, 64);
        if (lane == 0) ent[n] = s;
    }
    __syncthreads();
    if (tid == 0) {
        float perp = 0.f;
        #pragma unroll
        for (int n = 0; n < 8; ++n) perp += expf(-ent[n]);
        float ls = 0.f;
        for (int j = 0; j < NLOSS; ++j) ls += lossAcc[j];
        outTail[0] = 0.25f * (ls / (float)OUT_ELEMS);
        outTail[1] = perp;
    }
}

extern "C" void kernel_launch(void* const* d_in, const int* in_sizes, int n_in,
                              void* d_out, int out_size, void* d_ws, size_t ws_size,
                              hipStream_t stream) {
    const float* x   = (const float*)d_in[0];
    const float* emb = (const float*)d_in[1];
    float* out = (float*)d_out;
    char*  ws  = (char*)d_ws;

    unsigned int* ef16u  = (unsigned int*)(ws + EF_OFF);
    float* e2p    = (float*)(ws + E2P_OFF);
    float* e2r    = (float*)(ws + E2R_OFF);
    int*   counts = (int*)(ws + CNT_OFF);
    float* lossA  = (float*)(ws + LOSS_OFF);

    vq_prep_kernel<<<(N_G * M_CB * D_DIM / 2 + 255) / 256, 256, 0, stream>>>(
        emb, ef16u, e2r, e2p, counts, lossA);
    vq_mfma_kernel<<<TOKENS / 256, 256, 0, stream>>>(
        x, emb, (const unsigned short*)ef16u, e2r, e2p, out, counts, lossA);
    vq_finalize_kernel<<<1, 256, 0, stream>>>(counts, lossA, out + OUT_ELEMS);
}

// Round 14
// 84.415 us; speedup vs baseline: 4.1443x; 1.0377x over previous
//
#include <hip/hip_runtime.h>
#include <cfloat>
#include <cstddef>

// VQEmbeddingEMA inference forward — consolidation: R12 single-buffer staging +
// prep-folded zeroing + barrier-free finalize.
// x:   [B=32, N*D=512, L=1024] f32
// emb: [N=8, M=512, D=64] f32
// out: quantized_st [B,512,L] (16777216 f32) ++ loss (1) ++ perplexity (1)

#define N_G   8
#define M_CB  512
#define D_DIM 64
#define B_SZ  32
#define L_SEQ 1024
#define TOKENS (N_G * B_SZ * L_SEQ)                     // 262144
#define OUT_ELEMS ((size_t)B_SZ * N_G * D_DIM * L_SEQ)  // 16777216
#define MARGIN 2560
#define NLOSS 64

typedef _Float16 f16x8 __attribute__((ext_vector_type(8)));
typedef float    f32x4 __attribute__((ext_vector_type(4)));

// ---------------- workspace layout ----------------
//   [0,       524288)  e_f16  : codebook as f16, scaled by -2:  [n][m][d]
//   [524288,  540672)  e2p    : 1.0f + ||e||^2   (prescreen C-init table)
//   [540672,  557056)  e2raw  : ||e||^2          (exact fp32 rescore table)
//   [557056,  573440)  counts : int histogram [n][m]
//   [573440,  573696)  lossAcc: float[64]
#define EF_OFF   0
#define E2P_OFF  524288
#define E2R_OFF  540672
#define CNT_OFF  557056
#define LOSS_OFF 573440

// ---- merged prep: ef16 conversion + e2 tables + counts/loss zeroing ----
__global__ void vq_prep_kernel(const float* __restrict__ emb,
                               unsigned int* __restrict__ ef,
                               float* __restrict__ e2raw,
                               float* __restrict__ e2p,
                               int* __restrict__ counts,
                               float* __restrict__ lossAcc) {
    const int i = blockIdx.x * blockDim.x + threadIdx.x;
    if (i < N_G * M_CB * D_DIM / 2) {
        float2 v = reinterpret_cast<const float2*>(emb)[i];
        _Float16 h0 = (_Float16)(-2.0f * v.x);
        _Float16 h1 = (_Float16)(-2.0f * v.y);
        unsigned int u0 = (unsigned int)__builtin_bit_cast(unsigned short, h0);
        unsigned int u1 = (unsigned int)__builtin_bit_cast(unsigned short, h1);
        ef[i] = u0 | (u1 << 16);
    }
    if (i < N_G * M_CB) {
        const float* e = emb + (size_t)i * D_DIM;
        float s0 = 0.f, s1 = 0.f, s2 = 0.f, s3 = 0.f;
        #pragma unroll
        for (int d = 0; d < D_DIM; d += 4) {
            s0 = fmaf(e[d+0], e[d+0], s0);
            s1 = fmaf(e[d+1], e[d+1], s1);
            s2 = fmaf(e[d+2], e[d+2], s2);
            s3 = fmaf(e[d+3], e[d+3], s3);
        }
        float s = (s0 + s1) + (s2 + s3);
        e2raw[i] = s;
        e2p[i] = 1.0f + s;
        counts[i] = 0;
    }
    if (i < NLOSS) lossAcc[i] = 0.f;
}

// ---------------- MFMA main kernel (R12: single-buffer staging + prefetch) ----------------
__global__ __launch_bounds__(256, 4)
void vq_mfma_kernel(const float* __restrict__ x,
                    const float* __restrict__ emb,
                    const unsigned short* __restrict__ ef16,
                    const float* __restrict__ e2raw,
                    const float* __restrict__ e2p,
                    float* __restrict__ out,
                    int* __restrict__ counts,
                    float* __restrict__ lossAcc) {
    __shared__ int hist[M_CB];
    __shared__ int cands[4][4][16][8];   // [wave][strip][col][4 lane-slots x top2]
    __shared__ __align__(16) short ebuf[4 * 16 * 72];   // 4 tiles x 16 rows x 72 shorts

    const int tid  = threadIdx.x;
    hist[tid] = 0;
    hist[tid + 256] = 0;

    const int lane = tid & 63;
    const int wv   = tid >> 6;
    const int cc   = lane & 15;          // token col within strip / A-row (m)
    const int kl   = lane >> 4;          // k-chunk id / D row-group
    const int kl4  = kl << 2;

    const int bb  = blockIdx.x;          // [0,1024)
    const int n   = bb >> 7;
    const int rem = bb & 127;
    const int b   = rem >> 2;
    const int l0  = ((rem & 3) << 8) + (wv << 6);   // wave's token base

    const float* __restrict__ xg = x + (size_t)(b * N_G + n) * D_DIM * L_SEQ;
    const unsigned short* __restrict__ eg16 = ef16 + (size_t)n * M_CB * D_DIM;
    const float* __restrict__ e2pg = e2p + n * M_CB;

    // staging coords (chunk ids tid, tid+256 of 512 per outer)
    const int st_t0 = tid >> 7;
    const int st_r0 = (tid >> 3) & 15;
    const int st_c0 = tid & 7;
    const int st_o0 = st_t0 * 1152 + st_r0 * 72 + st_c0 * 8;
    const int st_o1 = (st_t0 + 2) * 1152 + st_r0 * 72 + st_c0 * 8;

    // ---- load X fragments (global -> f16), accumulate Sum(x^2) on the fly ----
    f16x8 xf[4][2];
    float x2p = 0.f;
    #pragma unroll
    for (int s = 0; s < 4; ++s) {
        const int tok = l0 + s * 16 + cc;
        #pragma unroll
        for (int kc = 0; kc < 2; ++kc) {
            const int dbase = kc * 32 + kl * 8;
            f16x8 v;
            #pragma unroll
            for (int j = 0; j < 8; ++j) {
                const float xs = xg[(size_t)(dbase + j) * L_SEQ + tok];
                x2p = fmaf(xs, xs, x2p);
                v[j] = (_Float16)xs;
            }
            xf[s][kc] = v;
        }
    }

    int t1[4], t2[4];
    #pragma unroll
    for (int s = 0; s < 4; ++s) { t1[s] = 0x7FFFFFFF; t2[s] = 0x7FFFFFFF; }

    // ---- prescreen: 8 outer chunks x 4 m-tiles; single-buffer staging,
    //      unconditional register prefetch of the next chunk ----
    uint4 g0 = *reinterpret_cast<const uint4*>(eg16 + tid * 8);
    uint4 g1 = *reinterpret_cast<const uint4*>(eg16 + 2048 + tid * 8);

    for (int outer = 0; outer < 8; ++outer) {
        *reinterpret_cast<uint4*>(&ebuf[st_o0]) = g0;
        *reinterpret_cast<uint4*>(&ebuf[st_o1]) = g1;
        __syncthreads();                 // ebuf ready

        // prefetch next chunk into registers (clamped index, always executed)
        {
            const int nxt = (outer < 7) ? outer + 1 : 7;
            const unsigned short* gsrc = eg16 + nxt * 4096 + tid * 8;
            g0 = *reinterpret_cast<const uint4*>(gsrc);
            g1 = *reinterpret_cast<const uint4*>(gsrc + 2048);
        }

        #pragma unroll
        for (int ml = 0; ml < 4; ++ml) {
            const short* erow = &ebuf[ml * 1152 + cc * 72 + kl * 8];
            const f16x8 ea0 = *reinterpret_cast<const f16x8*>(erow);
            const f16x8 ea1 = *reinterpret_cast<const f16x8*>(erow + 32);
            const int mt = outer * 4 + ml;
            const f32x4 ce2 = *reinterpret_cast<const f32x4*>(e2pg + mt * 16 + kl4);
            const int mb = mt * 16 + kl4;

            #pragma unroll
            for (int s = 0; s < 4; ++s) {
                f32x4 dacc = __builtin_amdgcn_mfma_f32_16x16x32_f16(ea0, xf[s][0], ce2,  0, 0, 0);
                dacc       = __builtin_amdgcn_mfma_f32_16x16x32_f16(ea1, xf[s][1], dacc, 0, 0, 0);
                // dacc[r] = 1 + e2 - 2*dot > 0: int-monotone after mask|idx pack
                const int p0 = (__float_as_int(dacc[0]) & ~511) | (mb + 0);
                const int p1 = (__float_as_int(dacc[1]) & ~511) | (mb + 1);
                const int p2 = (__float_as_int(dacc[2]) & ~511) | (mb + 2);
                const int p3 = (__float_as_int(dacc[3]) & ~511) | (mb + 3);
                int mn = min(p0, p1), mx = max(p0, p1);
                t2[s] = min(t2[s], max(min(t1[s], mx), mn));   // med3(t1,p0,p1)
                t1[s] = min(t1[s], mn);
                mn = min(p2, p3); mx = max(p2, p3);
                t2[s] = min(t2[s], max(min(t1[s], mx), mn));
                t1[s] = min(t1[s], mn);
            }
        }
        __syncthreads();                 // all reads done before next write
    }

    // ---- hand candidates to owning lane via LDS ----
    #pragma unroll
    for (int s = 0; s < 4; ++s) {
        cands[wv][s][cc][kl * 2 + 0] = t1[s];
        cands[wv][s][cc][kl * 2 + 1] = t2[s];
    }
    __syncthreads();

    const int tok = l0 + lane;           // lane owns token: strip = kl, col = cc
    int cd[8];
    #pragma unroll
    for (int j = 0; j < 8; ++j) cd[j] = cands[wv][kl][cc][j];
    int pmin = cd[0];
    #pragma unroll
    for (int j = 1; j < 8; ++j) pmin = min(pmin, cd[j]);

    // ---- reload this token's x column (fp32, coalesced, L2-hot) ----
    float xv[D_DIM];
    #pragma unroll
    for (int d = 0; d < D_DIM; ++d)
        xv[d] = xg[(size_t)d * L_SEQ + tok];

    // ---- exact fp32 rescore of near-minimal candidates (validated path) ----
    const float* __restrict__ eg  = emb + (size_t)n * M_CB * D_DIM;
    const float* __restrict__ e2g = e2raw + n * M_CB;
    float best1 = FLT_MAX, best2 = FLT_MAX;
    int   idx1  = 0x7FFFFFFF, idx2 = 0x7FFFFFFF;
    for (int j = 0; j < 8; ++j) {
        if (cd[j] - pmin <= MARGIN) {
            const int m = cd[j] & 511;
            const float4* em4 = reinterpret_cast<const float4*>(eg + (size_t)m * D_DIM);
            float a0 = 0.f, a1 = 0.f, a2 = 0.f, a3 = 0.f;
            #pragma unroll
            for (int q = 0; q < 16; ++q) {
                const float4 e4 = em4[q];
                a0 = fmaf(xv[q*4+0], e4.x, a0);
                a1 = fmaf(xv[q*4+1], e4.y, a1);
                a2 = fmaf(xv[q*4+2], e4.z, a2);
                a3 = fmaf(xv[q*4+3], e4.w, a3);
            }
            const float dist = fmaf(-2.f, (a0 + a1) + (a2 + a3), e2g[m]);
            if (dist < best1 || (dist == best1 && m < idx1)) {
                best2 = best1; idx2 = idx1; best1 = dist; idx1 = m;
            } else if (dist < best2 || (dist == best2 && m < idx2)) {
                best2 = dist; idx2 = m;
            }
        }
    }

    // ---- fp64 rescue for near-ties (validated semantics) ----
    if (best2 - best1 < 1e-4f) {
        const float* eA = eg + (size_t)idx1 * D_DIM;
        const float* eB = eg + (size_t)idx2 * D_DIM;
        double dA = 0.0, dB = 0.0;
        #pragma unroll
        for (int d = 0; d < D_DIM; ++d) {
            const double da = (double)xv[d] - (double)eA[d];
            const double db = (double)xv[d] - (double)eB[d];
            dA = fma(da, da, dA);
            dB = fma(db, db, dB);
        }
        if (dB < dA || (dB == dA && idx2 < idx1)) { idx1 = idx2; best1 = best2; }
    }

    // ---- epilogue: out = q; loss = Sum(x^2) + best dist; histogram ----
    const size_t obase = (size_t)(b * N_G + n) * D_DIM * L_SEQ + (size_t)tok;
    const float* __restrict__ ebest = eg + (size_t)idx1 * D_DIM;
    #pragma unroll
    for (int d = 0; d < D_DIM; d += 4) {
        const float4 qv = *reinterpret_cast<const float4*>(ebest + d);
        out[obase + (size_t)(d+0) * L_SEQ] = qv.x;
        out[obase + (size_t)(d+1) * L_SEQ] = qv.y;
        out[obase + (size_t)(d+2) * L_SEQ] = qv.z;
        out[obase + (size_t)(d+3) * L_SEQ] = qv.w;
    }

    float sq = x2p + best1;
    #pragma unroll
    for (int off = 32; off > 0; off >>= 1)
        sq += __shfl_down(sq, off, 64);
    if (lane == 0)
        atomicAdd(&lossAcc[bb & (NLOSS - 1)], sq);

    atomicAdd(&hist[idx1], 1);
    __syncthreads();
    {
        const int base = n * M_CB;
        int c0 = hist[tid];
        int c1 = hist[tid + 256];
        if (c0) atomicAdd(&counts[base + tid], c0);
        if (c1) atomicAdd(&counts[base + tid + 256], c1);
    }
}

// ---- barrier-free finalize: wave w reduces n=2w,2w+1; one barrier total ----
__global__ void vq_finalize_kernel(const int* __restrict__ counts,
                                   const float* __restrict__ lossAcc,
                                   float* __restrict__ outTail) {
    __shared__ float ent[8];
    const int tid  = threadIdx.x;
    const int lane = tid & 63;
    const int wvid = tid >> 6;           // 4 waves

    #pragma unroll
    for (int h = 0; h < 2; ++h) {
        const int n = wvid * 2 + h;
        float s = 0.f;
        #pragma unroll
        for (int r = 0; r < 8; ++r) {
            const float p = (float)counts[n * M_CB + r * 64 + lane] * (1.0f / (B_SZ * L_SEQ));
            s += p * logf(p + 1e-10f);
        }
        #pragma unroll
        for (int off = 32; off > 0; off >>= 1)
            s += __shfl_down(s, off, 64);
        if (lane == 0) ent[n] = s;
    }
    __syncthreads();
    if (tid == 0) {
        float perp = 0.f;
        #pragma unroll
        for (int n = 0; n < 8; ++n) perp += expf(-ent[n]);
        float ls = 0.f;
        for (int j = 0; j < NLOSS; ++j) ls += lossAcc[j];
        outTail[0] = 0.25f * (ls / (float)OUT_ELEMS);
        outTail[1] = perp;
    }
}

extern "C" void kernel_launch(void* const* d_in, const int* in_sizes, int n_in,
                              void* d_out, int out_size, void* d_ws, size_t ws_size,
                              hipStream_t stream) {
    const float* x   = (const float*)d_in[0];
    const float* emb = (const float*)d_in[1];
    float* out = (float*)d_out;
    char*  ws  = (char*)d_ws;

    unsigned int* ef16u  = (unsigned int*)(ws + EF_OFF);
    float* e2p    = (float*)(ws + E2P_OFF);
    float* e2r    = (float*)(ws + E2R_OFF);
    int*   counts = (int*)(ws + CNT_OFF);
    float* lossA  = (float*)(ws + LOSS_OFF);

    vq_prep_kernel<<<(N_G * M_CB * D_DIM / 2 + 255) / 256, 256, 0, stream>>>(
        emb, ef16u, e2r, e2p, counts, lossA);
    vq_mfma_kernel<<<TOKENS / 256, 256, 0, stream>>>(
        x, emb, (const unsigned short*)ef16u, e2r, e2p, out, counts, lossA);
    vq_finalize_kernel<<<1, 256, 0, stream>>>(counts, lossA, out + OUT_ELEMS);
}